// Round 5
// baseline (130.862 us; speedup 1.0000x reference)
//
#include <hip/hip_runtime.h>
#include <hip/hip_bf16.h>

#define NB 16
#define SEQ 2048
#define EDIM 256

typedef __attribute__((ext_vector_type(16))) float f32x16;
typedef __attribute__((ext_vector_type(4)))  float f32x4;
typedef __attribute__((ext_vector_type(8)))  short short8;
typedef __attribute__((ext_vector_type(4)))  short short4v;

static __device__ __forceinline__ ushort f2bf(float f) {
    uint32_t u = __float_as_uint(f);
    uint32_t r = (u + 0x7fffu + ((u >> 16) & 1u)) >> 16;
    return (ushort)r;
}
static __device__ __forceinline__ float bf2f(ushort h) {
    return __uint_as_float(((uint32_t)h) << 16);
}

// async global->LDS, 16 bytes per lane; LDS dest wave-uniform, global src per-lane.
static __device__ __forceinline__ void gll16(const ushort* g, ushort* l) {
    __builtin_amdgcn_global_load_lds(
        (const __attribute__((address_space(1))) uint32_t*)g,
        (__attribute__((address_space(3))) uint32_t*)l,
        16, 0, 0);
}

// Kernel 1: fp32 -> bf16 in K-MAJOR PANEL layout xb[b][ks][t][j] (ks=e>>4,
// j=e&15), plus per-row sum of squares of the bf16-rounded values (distance
// diagonal then cancels exactly against the fp32-accumulated MFMA gram).
// x is read once -> non-temporal, so it doesn't evict xb from L2/LLC.
__global__ void prep_kernel(const float* __restrict__ x,
                            ushort* __restrict__ xb,
                            float* __restrict__ sq) {
    __shared__ ushort sh[4][256];
    const int tid  = threadIdx.x;
    const int r    = tid >> 6;
    const int lane = tid & 63;
    const int grow = blockIdx.x * 4;
    const int row  = grow + r;

    const f32x4* xp = reinterpret_cast<const f32x4*>(x + (size_t)row * EDIM + lane * 4);
    const f32x4 v = __builtin_nontemporal_load(xp);
    ushort h0 = f2bf(v.x), h1 = f2bf(v.y), h2 = f2bf(v.z), h3 = f2bf(v.w);
    ushort4 h; h.x = h0; h.y = h1; h.z = h2; h.w = h3;
    *reinterpret_cast<ushort4*>(&sh[r][lane * 4]) = h;

    const float fx = bf2f(h0), fy = bf2f(h1), fz = bf2f(h2), fw = bf2f(h3);
    float s = fx * fx + fy * fy + fz * fz + fw * fw;
    #pragma unroll
    for (int m = 1; m < 64; m <<= 1) s += __shfl_xor(s, m);
    if (lane == 0) sq[row] = s;

    __syncthreads();

    const int b   = grow >> 11;
    const int t0  = grow & 2047;
    const int ksx = tid >> 4;           // 0..15
    const int idx = tid & 15;
    const int r2  = idx >> 2;
    const int j   = (idx & 3) * 4;
    ushort4 o = *reinterpret_cast<ushort4*>(&sh[r2][ksx * 16 + j]);
    *reinterpret_cast<ushort4*>(xb + (size_t)b * SEQ * EDIM
                                   + (size_t)ksx * SEQ * 16
                                   + (size_t)(t0 + r2) * 16 + j) = o;
}

// Kernel 2: fused gram-GEMM + one-pass softmax. WG = 32 rows x 2048 cols,
// 8 waves; wave w owns cols [w*256,(w+1)*256). B fragments load DIRECTLY
// from global (k-major layout -> each fragment is a contiguous, coalesced
// 1 KB wave read; B is wave-private so LDS staging buys nothing). Only the
// shared A panel (16 KB) goes through LDS, staged once behind one barrier.
// grid.x = batch so flat_wgid % 8 == batch % 8: all WGs of a batch land on
// one XCD -> its 1 MB panel set stays L2-resident (2 batches/XCD = 2 MB).
// Output stores are non-temporal (write-once stream, keep L2 for panels).
__global__ __launch_bounds__(512, 2) void sims_main(
        const ushort* __restrict__ xb,
        const float*  __restrict__ sq,
        float* __restrict__ out) {
    __shared__ __align__(16) ushort Ab[16 * 512];   // 16 KB: [ks][64 chunks][8]
    __shared__ float red[32][9];
    __shared__ float inv[32];

    const int b      = blockIdx.x;      // batch -> XCD = b % 8
    const int rowblk = blockIdx.y;
    const int tid    = threadIdx.x;
    const int wave   = tid >> 6;
    const int lane   = tid & 63;
    const int l31    = lane & 31;
    const int hi     = lane >> 5;

    const int row_base = rowblk * 32;
    const ushort* xbB = xb + (size_t)b * SEQ * EDIM;

    // ---- stage A panel: wave w stages ks = 2w, 2w+1; one barrier total.
    {
        const int gl   = lane ^ ((lane >> 3) & 7);   // src chunk (involution)
        const int r    = gl >> 1;
        const int half = gl & 1;
        #pragma unroll
        for (int i = 0; i < 2; ++i) {
            const int ksa = wave * 2 + i;
            gll16(xbB + (size_t)ksa * (SEQ * 16) + (row_base + r) * 16 + half * 8,
                  Ab + ksa * 512);
        }
    }
    asm volatile("s_waitcnt vmcnt(0)" ::: "memory");
    __builtin_amdgcn_s_barrier();
    __builtin_amdgcn_sched_barrier(0);

    f32x16 acc[8];
    #pragma unroll
    for (int cb = 0; cb < 8; ++cb) acc[cb] = (f32x16)0.0f;

    const int r6  = l31 * 2 + hi;
    const int pr6 = r6 ^ ((r6 >> 3) & 7);            // swizzled A read position

    const int col_base = wave * 256;
    // lane's B address inside a k-step panel: col = col_base + cb*32 + l31,
    // 16B half selected by hi. cb steps are 1 KB apart (imm-offset friendly).
    const ushort* bbase = xbB + ((size_t)col_base + l31) * 16 + hi * 8;

    #pragma unroll 1
    for (int ks = 0; ks < 16; ++ks) {
        const ushort* bks = bbase + (size_t)ks * (SEQ * 16);
        short8 bv[8];
        #pragma unroll
        for (int cb = 0; cb < 8; ++cb)
            bv[cb] = *reinterpret_cast<const short8*>(bks + cb * 512);
        const short8 a = *reinterpret_cast<const short8*>(Ab + ks * 512 + pr6 * 8);
        #pragma unroll
        for (int cb = 0; cb < 8; ++cb)
            acc[cb] = __builtin_amdgcn_mfma_f32_32x32x16_bf16(a, bv[cb], acc[cb], 0, 0, 0);
    }

    // ---- epilogue: exp(-dist/T), row sums, scale, store (verified R0-R2) ----
    constexpr float kC = (float)(-1.4426950408889634 / 13.544);  // -log2(e)/T
    const float* sqB = sq + b * SEQ;
    float sqc[8];
    #pragma unroll
    for (int cb = 0; cb < 8; ++cb) sqc[cb] = sqB[col_base + cb * 32 + l31];
    float sqr[16];
    #pragma unroll
    for (int r = 0; r < 16; ++r) sqr[r] = sqB[row_base + (r & 3) + 8 * (r >> 2) + 4 * hi];

    float part[16];
    #pragma unroll
    for (int r = 0; r < 16; ++r) {
        float p = 0.0f;
        #pragma unroll
        for (int cb = 0; cb < 8; ++cb) {
            const float d = sqr[r] + sqc[cb] - 2.0f * acc[cb][r];
            const float e = exp2f(d * kC);
            acc[cb][r] = e;
            p += e;
        }
        part[r] = p;
    }
    #pragma unroll
    for (int r = 0; r < 16; ++r) {
        float p = part[r];
        p += __shfl_xor(p, 1);
        p += __shfl_xor(p, 2);
        p += __shfl_xor(p, 4);
        p += __shfl_xor(p, 8);
        p += __shfl_xor(p, 16);
        part[r] = p;
    }

    if (l31 == 0) {
        #pragma unroll
        for (int r = 0; r < 16; ++r) {
            const int lrow = (r & 3) + 8 * (r >> 2) + 4 * hi;
            red[lrow][wave] = part[r];
        }
    }
    __syncthreads();
    if (tid < 32) {
        float s = 0.0f;
        #pragma unroll
        for (int w = 0; w < 8; ++w) s += red[tid][w];
        inv[tid] = 1.0f / s;
    }
    __syncthreads();

    float invr[16];
    #pragma unroll
    for (int r = 0; r < 16; ++r) invr[r] = inv[(r & 3) + 8 * (r >> 2) + 4 * hi];

    float* outB = out + (size_t)b * SEQ * SEQ;
    #pragma unroll
    for (int r = 0; r < 16; ++r) {
        const int lrow = (r & 3) + 8 * (r >> 2) + 4 * hi;
        float* orow = outB + (size_t)(row_base + lrow) * SEQ + col_base + l31;
        const float scale = invr[r];
        #pragma unroll
        for (int cb = 0; cb < 8; ++cb) {
            __builtin_nontemporal_store(acc[cb][r] * scale, &orow[cb * 32]);
        }
    }
}

extern "C" void kernel_launch(void* const* d_in, const int* in_sizes, int n_in,
                              void* d_out, int out_size, void* d_ws, size_t ws_size,
                              hipStream_t stream) {
    (void)in_sizes; (void)n_in; (void)out_size; (void)ws_size;
    const float* x = (const float*)d_in[0];
    float* out = (float*)d_out;

    ushort* xb = (ushort*)d_ws;                                       // 16 MB bf16, k-major panels
    float*  sq = (float*)((char*)d_ws + (size_t)NB * SEQ * EDIM * 2); // 128 KB row norms

    prep_kernel<<<NB * SEQ / 4, 256, 0, stream>>>(x, xb, sq);

    dim3 grid(NB, SEQ / 32);   // x = batch: flat%8 == batch%8 -> XCD locality
    sims_main<<<grid, 512, 0, stream>>>(xb, sq, out);
}

// Round 8
// 118.653 us; speedup vs baseline: 1.1029x; 1.1029x over previous
//
#include <hip/hip_runtime.h>
#include <hip/hip_bf16.h>

#define NB 16
#define SEQ 2048
#define EDIM 256

typedef __attribute__((ext_vector_type(16))) float f32x16;
typedef __attribute__((ext_vector_type(4)))  float f32x4;
typedef __attribute__((ext_vector_type(8)))  short short8;

static __device__ __forceinline__ ushort f2bf(float f) {
    uint32_t u = __float_as_uint(f);
    uint32_t r = (u + 0x7fffu + ((u >> 16) & 1u)) >> 16;
    return (ushort)r;
}
static __device__ __forceinline__ float bf2f(ushort h) {
    return __uint_as_float(((uint32_t)h) << 16);
}

// async global->LDS, 16 bytes per lane; LDS dest wave-uniform, global src per-lane.
static __device__ __forceinline__ void gll16(const ushort* g, ushort* l) {
    __builtin_amdgcn_global_load_lds(
        (const __attribute__((address_space(1))) uint32_t*)g,
        (__attribute__((address_space(3))) uint32_t*)l,
        16, 0, 0);
}

// Kernel 1: fp32 -> bf16 in K-MAJOR PANEL layout xb[b][ks][t][j] (ks=e>>4,
// j=e&15), plus per-row sum of squares of the bf16-rounded values (distance
// diagonal cancels exactly against the fp32-accumulated MFMA gram).
__global__ void prep_kernel(const float* __restrict__ x,
                            ushort* __restrict__ xb,
                            float* __restrict__ sq) {
    __shared__ ushort sh[4][256];
    const int tid  = threadIdx.x;
    const int r    = tid >> 6;
    const int lane = tid & 63;
    const int grow = blockIdx.x * 4;
    const int row  = grow + r;

    const f32x4* xp = reinterpret_cast<const f32x4*>(x + (size_t)row * EDIM + lane * 4);
    const f32x4 v = __builtin_nontemporal_load(xp);
    ushort h0 = f2bf(v.x), h1 = f2bf(v.y), h2 = f2bf(v.z), h3 = f2bf(v.w);
    ushort4 h; h.x = h0; h.y = h1; h.z = h2; h.w = h3;
    *reinterpret_cast<ushort4*>(&sh[r][lane * 4]) = h;

    const float fx = bf2f(h0), fy = bf2f(h1), fz = bf2f(h2), fw = bf2f(h3);
    float s = fx * fx + fy * fy + fz * fz + fw * fw;
    #pragma unroll
    for (int m = 1; m < 64; m <<= 1) s += __shfl_xor(s, m);
    if (lane == 0) sq[row] = s;

    __syncthreads();

    const int b   = grow >> 11;
    const int t0  = grow & 2047;
    const int ksx = tid >> 4;           // 0..15
    const int idx = tid & 15;
    const int r2  = idx >> 2;
    const int j   = (idx & 3) * 4;
    ushort4 o = *reinterpret_cast<ushort4*>(&sh[r2][ksx * 16 + j]);
    *reinterpret_cast<ushort4*>(xb + (size_t)b * SEQ * EDIM
                                   + (size_t)ksx * SEQ * 16
                                   + (size_t)(t0 + r2) * 16 + j) = o;
}

// Kernel 2: fused gram-GEMM + one-pass softmax. WG = 1024 thr (16 waves),
// 32 rows x FULL 2048 cols (softmax denominator needs the whole row —
// splitting cols across WGs was the R5/R6 bug). Wave w owns cols
// [w*128,(w+1)*128) = 4 cb -> acc is only 64 VGPRs/lane; launch_bounds
// caps at 128 VGPR so the 16-wave WG fits and 4 waves/SIMD hide latency.
// B fragments load directly from global (k-major panels -> coalesced);
// A staged once to LDS (swizzled chunks, one barrier). nt output stores.
__global__ __launch_bounds__(1024, 4) void sims_main(
        const ushort* __restrict__ xb,
        const float*  __restrict__ sq,
        float* __restrict__ out) {
    __shared__ __align__(16) ushort Ab[16 * 512];   // 16 KB: [ks][64 chunks][8]
    __shared__ float red[32][17];
    __shared__ float inv[32];

    const int b      = blockIdx.x;      // batch -> XCD = b % 8 (16%8==0)
    const int rowblk = blockIdx.y;
    const int tid    = threadIdx.x;
    const int wave   = tid >> 6;        // 0..15
    const int lane   = tid & 63;
    const int l31    = lane & 31;
    const int hi     = lane >> 5;

    const int row_base = rowblk * 32;
    const ushort* xbB = xb + (size_t)b * SEQ * EDIM;

    // ---- stage A panel: wave w stages k-slice ks=w (1 KB); one barrier.
    {
        const int gl = lane ^ ((lane >> 3) & 7);    // src chunk (involution)
        gll16(xbB + (size_t)wave * (SEQ * 16) + (row_base + (gl >> 1)) * 16 + (gl & 1) * 8,
              Ab + wave * 512);
    }
    asm volatile("s_waitcnt vmcnt(0)" ::: "memory");
    __builtin_amdgcn_s_barrier();
    __builtin_amdgcn_sched_barrier(0);

    f32x16 acc[4];
    #pragma unroll
    for (int cb = 0; cb < 4; ++cb) acc[cb] = (f32x16)0.0f;

    const int r6  = l31 * 2 + hi;
    const int pr6 = r6 ^ ((r6 >> 3) & 7);           // swizzled A read chunk

    const int colw = wave * 128;
    // lane's B address in a k-step panel: col = colw + cb*32 + l31, half hi.
    const ushort* bbase = xbB + ((size_t)colw + l31) * 16 + hi * 8;

    #pragma unroll 2
    for (int ks = 0; ks < 16; ++ks) {
        const ushort* bks = bbase + (size_t)ks * (SEQ * 16);
        short8 bv[4];
        #pragma unroll
        for (int cb = 0; cb < 4; ++cb)
            bv[cb] = *reinterpret_cast<const short8*>(bks + cb * 512);
        const short8 a = *reinterpret_cast<const short8*>(Ab + ks * 512 + pr6 * 8);
        #pragma unroll
        for (int cb = 0; cb < 4; ++cb)
            acc[cb] = __builtin_amdgcn_mfma_f32_32x32x16_bf16(a, bv[cb], acc[cb], 0, 0, 0);
    }

    // ---- epilogue: exp(-dist/T), full-row sums, scale, store ----
    constexpr float kC = (float)(-1.4426950408889634 / 13.544);  // -log2(e)/T
    const float* sqB = sq + b * SEQ;
    float sqc[4];
    #pragma unroll
    for (int cb = 0; cb < 4; ++cb) sqc[cb] = sqB[colw + cb * 32 + l31];

    float part[16];
    #pragma unroll
    for (int r = 0; r < 16; ++r) {
        const float sqr = sqB[row_base + (r & 3) + 8 * (r >> 2) + 4 * hi];
        float p = 0.0f;
        #pragma unroll
        for (int cb = 0; cb < 4; ++cb) {
            const float d = sqr + sqc[cb] - 2.0f * acc[cb][r];
            const float e = exp2f(d * kC);
            acc[cb][r] = e;
            p += e;
        }
        part[r] = p;
    }
    #pragma unroll
    for (int r = 0; r < 16; ++r) {
        float p = part[r];
        p += __shfl_xor(p, 1);
        p += __shfl_xor(p, 2);
        p += __shfl_xor(p, 4);
        p += __shfl_xor(p, 8);
        p += __shfl_xor(p, 16);
        part[r] = p;
    }

    if (l31 == 0) {                      // lanes 0 and 32 of each wave
        #pragma unroll
        for (int r = 0; r < 16; ++r) {
            const int lrow = (r & 3) + 8 * (r >> 2) + 4 * hi;
            red[lrow][wave] = part[r];
        }
    }
    __syncthreads();
    if (tid < 32) {
        float s = 0.0f;
        #pragma unroll
        for (int w = 0; w < 16; ++w) s += red[tid][w];
        inv[tid] = 1.0f / s;
    }
    __syncthreads();

    float* outB = out + (size_t)b * SEQ * SEQ;
    #pragma unroll
    for (int r = 0; r < 16; ++r) {
        const int lrow = (r & 3) + 8 * (r >> 2) + 4 * hi;
        const float scale = inv[lrow];
        float* orow = outB + (size_t)(row_base + lrow) * SEQ + colw + l31;
        #pragma unroll
        for (int cb = 0; cb < 4; ++cb) {
            __builtin_nontemporal_store(acc[cb][r] * scale, &orow[cb * 32]);
        }
    }
}

extern "C" void kernel_launch(void* const* d_in, const int* in_sizes, int n_in,
                              void* d_out, int out_size, void* d_ws, size_t ws_size,
                              hipStream_t stream) {
    (void)in_sizes; (void)n_in; (void)out_size; (void)ws_size;
    const float* x = (const float*)d_in[0];
    float* out = (float*)d_out;

    ushort* xb = (ushort*)d_ws;                                       // 16 MB bf16, k-major panels
    float*  sq = (float*)((char*)d_ws + (size_t)NB * SEQ * EDIM * 2); // 128 KB row norms

    prep_kernel<<<NB * SEQ / 4, 256, 0, stream>>>(x, xb, sq);

    dim3 grid(NB, SEQ / 32);   // x = batch: flat%8 == batch%8 -> XCD locality
    sims_main<<<grid, 1024, 0, stream>>>(xb, sq, out);
}